// Round 9
// baseline (488.449 us; speedup 1.0000x reference)
//
#include <hip/hip_runtime.h>
#include <hip/hip_bf16.h>
#include <math.h>

#define B_DIM 4096
#define D_IN  2048
#define D_HID 3584
#define D_OUT 2048

typedef __bf16 bf16;
typedef float  floatx4 __attribute__((ext_vector_type(4)));
typedef bf16   bf16x8  __attribute__((ext_vector_type(8)));
typedef bf16   bf16x4  __attribute__((ext_vector_type(4)));

typedef __attribute__((address_space(1))) const void* gptr1;
typedef __attribute__((address_space(3))) void*       lptr3;

__device__ __forceinline__ void load_lds16(const void* g, void* l) {
    __builtin_amdgcn_global_load_lds((gptr1)g, (lptr3)l, 16, 0, 0);
}

struct HL { bf16 h, l; };
__device__ __forceinline__ HL split2(float v) {
    HL r;
    r.h = (bf16)v;
    r.l = (bf16)(v - (float)r.h);
    return r;
}

// T1 XCD-aware tile remap (bijective for nwg = 512, nwg%8==0).
__device__ __forceinline__ void xcd_tile(int& n0, int& m0) {
    const int d  = (int)(blockIdx.x + gridDim.x * blockIdx.y);
    const int r  = d >> 3;
    const int nx = ((d & 7) << 1) | (r & 1);
    const int my = r >> 1;
    n0 = nx * 128;
    m0 = my * 128;
}

// ---------------------------------------------------------------------------
// Fused prep (verified round 7/8): vesica | tsplit | wcat by blockIdx range.
// ---------------------------------------------------------------------------
__global__ __launch_bounds__(256) void prep_kernel(const float* __restrict__ x,
                                                   const float* __restrict__ Wfl,
                                                   const float* __restrict__ Wm,
                                                   const float* __restrict__ Wfe,
                                                   bf16* __restrict__ xh,
                                                   bf16* __restrict__ xl,
                                                   bf16* __restrict__ th,
                                                   bf16* __restrict__ tl,
                                                   bf16* __restrict__ wh,
                                                   bf16* __restrict__ wl) {
    __shared__ float tile[64][65];
    const int id = blockIdx.x;
    const int t  = threadIdx.x;

    if (id < 4096) {
        const int b  = id;
        const int bp = (b == 0) ? (B_DIM - 1) : (b - 1);

        const floatx4* xr = (const floatx4*)(x + (size_t)b  * D_IN);
        const floatx4* pr = (const floatx4*)(x + (size_t)bp * D_IN);
        const floatx4 v0 = xr[t * 2], v1 = xr[t * 2 + 1];
        const floatx4 p0 = pr[t * 2], p1 = pr[t * 2 + 1];

        float s = 0.f;
#pragma unroll
        for (int j = 0; j < 4; ++j) {
            const float d0 = v0[j] - p0[j], d1 = v1[j] - p1[j];
            s += d0 * d0 + d1 * d1;
        }
#pragma unroll
        for (int off = 32; off > 0; off >>= 1) s += __shfl_down(s, off, 64);

        float* red = &tile[0][0];
        const int wave = t >> 6, lane = t & 63;
        if (lane == 0) red[wave] = s;
        __syncthreads();
        const float dist = sqrtf(red[0] + red[1] + red[2] + red[3]);
        const float sc   = 1.f + fmaxf(0.f, 1.f - fabsf(dist - 1.f));

        bf16x8 h, l;
#pragma unroll
        for (int j = 0; j < 4; ++j) {
            const HL a  = split2(v0[j] * sc);
            const HL b2 = split2(v1[j] * sc);
            h[j] = a.h;      l[j] = a.l;
            h[4 + j] = b2.h; l[4 + j] = b2.l;
        }
        ((bf16x8*)(xh + (size_t)b * D_IN))[t] = h;
        ((bf16x8*)(xl + (size_t)b * D_IN))[t] = l;

    } else if (id < 4096 + 1792) {
        const int tb = id - 4096;
        const int d0 = (tb & 31) << 6;
        const int h0 = (tb >> 5) << 6;
        const int r  = t >> 4;
        const int cg = (t & 15) << 2;

#pragma unroll
        for (int i = 0; i < 4; ++i) {
            const int hr = r + i * 16;
            const floatx4 v = *(const floatx4*)&Wfl[(size_t)(h0 + hr) * 2048 + d0 + cg];
            tile[hr][cg]     = v[0];
            tile[hr][cg + 1] = v[1];
            tile[hr][cg + 2] = v[2];
            tile[hr][cg + 3] = v[3];
        }
        __syncthreads();

        float pm[4];
#pragma unroll
        for (int j = 0; j < 4; ++j) {
            const int h  = h0 + cg + j;
            const int hm = h & 511;
            float p = 1.f;
            if (hm < 2) {
                const float ph = 0.8975979010256552f * (float)(h >> 9);
                p = (hm == 0) ? cosf(ph) : sinf(ph);
            }
            pm[j] = p;
        }

#pragma unroll
        for (int i = 0; i < 4; ++i) {
            const int dr = r + i * 16;
            bf16x4 hh, ll;
#pragma unroll
            for (int j = 0; j < 4; ++j) {
                const HL u = split2(tile[cg + j][dr] * pm[j]);
                hh[j] = u.h;
                ll[j] = u.l;
            }
            const size_t o = (size_t)(d0 + dr) * 3584 + h0 + cg;
            *(bf16x4*)&th[o] = hh;
            *(bf16x4*)&tl[o] = ll;
        }

    } else {
        const int i = (id - 5888) * 256 + t;
        const int o = i / 448;
        const int g = i - o * 448;
        bf16x8 h, l;
        if (o < 2048) {
            const float* src = Wm + (size_t)o * 3584 + (size_t)g * 8;
            const floatx4 a = ((const floatx4*)src)[0];
            const floatx4 b = ((const floatx4*)src)[1];
#pragma unroll
            for (int j = 0; j < 4; ++j) {
                const HL u = split2(a[j]);
                const HL v = split2(b[j]);
                h[j] = u.h;     l[j] = u.l;
                h[4 + j] = v.h; l[4 + j] = v.l;
            }
        } else {
            const float* src = Wfe + (size_t)(o - 2048) * 3584 + (size_t)(447 - g) * 8;
            const floatx4 a = ((const floatx4*)src)[0];
            const floatx4 b = ((const floatx4*)src)[1];
#pragma unroll
            for (int j = 0; j < 4; ++j) {
                const HL u = split2(b[3 - j]);
                const HL v = split2(a[3 - j]);
                h[j] = u.h;     l[j] = u.l;
                h[4 + j] = v.h; l[4 + j] = v.l;
            }
        }
        ((bf16x8*)wh)[i] = h;
        ((bf16x8*)wl)[i] = l;
    }
}

// ---------------------------------------------------------------------------
// 8-phase bf16x3 GEMM (m201-style schedule), C = A @ B^T, bf16 hi/lo out.
// BM=256, BN=128, BK=32 half-tiles. 512 thr = 8 waves (4M x 2N, wave 64x64).
// LDS: 3-slot ring x 48KB (A hi 16K | A lo 16K | B hi 8K | B lo 8K) = 144KB,
// 1 block/CU, grid 16x16 = 256 = 1 block per CU exactly.
// Pipeline: prefetch depth 2; per half-tile h:
//   s_waitcnt vmcnt(6)   <- h's 6 loads done; h+1's 6 stay in flight (T4)
//   s_barrier            <- all waves' h loads landed
//   phase0: issue A-gloads(h+2) | ds_read A[0,1]+B[0..3] | 24 MFMA (setprio)
//   s_barrier
//   phase1: issue B-gloads(h+2) | ds_read A[2,3]          | 24 MFMA (setprio)
// Staging + read swizzle are the verified r5-dual involution (0 conflicts):
// chunk q stored linearly, global src chunk p = q ^ ((q>>3)&7); read
// off = (((row<<2)+cq) ^ (lr>>1)) << 3.
// ---------------------------------------------------------------------------
__global__ __launch_bounds__(512, 2) void gemm3_single8(const bf16* __restrict__ Ah,
                                                        const bf16* __restrict__ Al,
                                                        const bf16* __restrict__ Bh,
                                                        const bf16* __restrict__ Bl,
                                                        bf16* __restrict__ C0,
                                                        bf16* __restrict__ C1,
                                                        int M, int N, int K) {
    __shared__ bf16 lds[3 * 24576];   // 144 KB

    const int tid  = threadIdx.x;
    const int wave = tid >> 6;
    const int lane = tid & 63;

    // XCD remap for 16x16 grid (256 blocks, bijective)
    const int d  = (int)(blockIdx.x + gridDim.x * blockIdx.y);
    const int rr = d >> 3;
    const int n0 = (((d & 7) << 1) | (rr & 1)) * 128;
    const int m0 = (rr >> 1) * 256;

    const int wm = wave >> 1;         // 0..3 (M)
    const int wn = wave & 1;          // 0..1 (N)

    floatx4 acc[4][4];
#pragma unroll
    for (int i = 0; i < 4; ++i)
#pragma unroll
        for (int j = 0; j < 4; ++j) acc[i][j] = (floatx4){0.f, 0.f, 0.f, 0.f};

    const int lr  = lane & 15;
    const int cq  = lane >> 4;        // logical chunk 0..3
    const int hsw = lr >> 1;          // == (row>>1)&7 for all fragment rows

    // A: 256 rows x 4 chunks = 1024; thread covers q and q+512. B: 512.
    auto stageA = [&](int h, int slot, int which) {
        const int q = (which << 9) + tid;            // 0..1023
        const int p = q ^ ((q >> 3) & 7);
        const int r = p >> 2, c = p & 3;
        const size_t ga = (size_t)(m0 + r) * K + (h << 5) + c * 8;
        bf16* base = &lds[slot * 24576];
        load_lds16(&Ah[ga], base + (q << 3));
        load_lds16(&Al[ga], base + 8192 + (q << 3));
    };
    auto stageB = [&](int h, int slot) {
        const int q = tid;                           // 0..511
        const int p = q ^ ((q >> 3) & 7);
        const int r = p >> 2, c = p & 3;
        const size_t gb = (size_t)(n0 + r) * K + (h << 5) + c * 8;
        bf16* base = &lds[slot * 24576 + 16384];
        load_lds16(&Bh[gb], base + (q << 3));
        load_lds16(&Bl[gb], base + 4096 + (q << 3));
    };

    auto halfstep = [&](int h, int slot, int slot2, bool issue) {
        const bf16* pAh = &lds[slot * 24576];
        const bf16* pAl = pAh + 8192;
        const bf16* pBh = pAh + 16384;
        const bf16* pBl = pAh + 20480;

        bf16x8 Afh[4], Afl[4], Bfh[4], Bfl[4];

        __builtin_amdgcn_s_barrier();              // all waves: h loads landed
        // ---- phase 0: A mi 0,1 + all B; 24 MFMA ----
        if (issue) { stageA(h + 2, slot2, 0); stageA(h + 2, slot2, 1); }
#pragma unroll
        for (int mi = 0; mi < 2; ++mi) {
            const int ql  = ((wm * 64 + mi * 16 + lr) << 2) + cq;
            const int off = (ql ^ hsw) << 3;
            Afh[mi] = *(const bf16x8*)&pAh[off];
            Afl[mi] = *(const bf16x8*)&pAl[off];
        }
#pragma unroll
        for (int ni = 0; ni < 4; ++ni) {
            const int ql  = ((wn * 64 + ni * 16 + lr) << 2) + cq;
            const int off = (ql ^ hsw) << 3;
            Bfh[ni] = *(const bf16x8*)&pBh[off];
            Bfl[ni] = *(const bf16x8*)&pBl[off];
        }
        __builtin_amdgcn_s_setprio(1);
#pragma unroll
        for (int mi = 0; mi < 2; ++mi)
#pragma unroll
            for (int ni = 0; ni < 4; ++ni) {
                acc[mi][ni] = __builtin_amdgcn_mfma_f32_16x16x32_bf16(
                    Afh[mi], Bfh[ni], acc[mi][ni], 0, 0, 0);
                acc[mi][ni] = __builtin_amdgcn_mfma_f32_16x16x32_bf16(
                    Afl[mi], Bfh[ni], acc[mi][ni], 0, 0, 0);
                acc[mi][ni] = __builtin_amdgcn_mfma_f32_16x16x32_bf16(
                    Afh[mi], Bfl[ni], acc[mi][ni], 0, 0, 0);
            }
        __builtin_amdgcn_s_setprio(0);
        __builtin_amdgcn_s_barrier();
        // ---- phase 1: A mi 2,3; 24 MFMA ----
        if (issue) stageB(h + 2, slot2);
#pragma unroll
        for (int mi = 2; mi < 4; ++mi) {
            const int ql  = ((wm * 64 + mi * 16 + lr) << 2) + cq;
            const int off = (ql ^ hsw) << 3;
            Afh[mi] = *(const bf16x8*)&pAh[off];
            Afl[mi] = *(const bf16x8*)&pAl[off];
        }
        __builtin_amdgcn_s_setprio(1);
#pragma unroll
        for (int mi = 2; mi < 4; ++mi)
#pragma unroll
            for (int ni = 0; ni < 4; ++ni) {
                acc[mi][ni] = __builtin_amdgcn_mfma_f32_16x16x32_bf16(
                    Afh[mi], Bfh[ni], acc[mi][ni], 0, 0, 0);
                acc[mi][ni] = __builtin_amdgcn_mfma_f32_16x16x32_bf16(
                    Afl[mi], Bfh[ni], acc[mi][ni], 0, 0, 0);
                acc[mi][ni] = __builtin_amdgcn_mfma_f32_16x16x32_bf16(
                    Afh[mi], Bfl[ni], acc[mi][ni], 0, 0, 0);
            }
        __builtin_amdgcn_s_setprio(0);
    };

    // prologue: stage half-tiles 0 and 1 (12 loads in flight)
    stageA(0, 0, 0); stageA(0, 0, 1); stageB(0, 0);
    stageA(1, 1, 0); stageA(1, 1, 1); stageB(1, 1);

    const int NH = K >> 5;            // 112 half-tiles
    int slot = 0, slot2 = 2;
    for (int h = 0; h < NH - 2; ++h) {
        asm volatile("s_waitcnt vmcnt(6)" ::: "memory");
        halfstep(h, slot, slot2, true);
        slot  = (slot  == 2) ? 0 : slot + 1;
        slot2 = (slot2 == 2) ? 0 : slot2 + 1;
    }
    // peeled tail: h = NH-2 (h+1 still in flight), h = NH-1 (drain)
    asm volatile("s_waitcnt vmcnt(6)" ::: "memory");
    halfstep(NH - 2, slot, slot2, false);
    slot = (slot == 2) ? 0 : slot + 1;
    asm volatile("s_waitcnt vmcnt(0)" ::: "memory");
    halfstep(NH - 1, slot, slot2, false);

    const int rq = (lane >> 4) << 2;
    const int cl = lane & 15;
#pragma unroll
    for (int mi = 0; mi < 4; ++mi) {
#pragma unroll
        for (int ni = 0; ni < 4; ++ni) {
            const int col = n0 + wn * 64 + ni * 16 + cl;
#pragma unroll
            for (int r = 0; r < 4; ++r) {
                const int row = m0 + wm * 64 + mi * 16 + rq + r;
                const size_t idx = (size_t)row * N + col;
                const HL u = split2(acc[mi][ni][r]);
                C0[idx] = u.h;
                C1[idx] = u.l;
            }
        }
    }
}

// ---------------------------------------------------------------------------
// Dual GEMM (bf16x3): male/female = xo @ {Wcm,Wcf}^T in ONE kernel.
// ROUND-5/8 VERBATIM (measured 0 bank conflicts) + T1 XCD tile remap.
// ---------------------------------------------------------------------------
__global__ __launch_bounds__(256, 2) void gemm3_dual(const bf16* __restrict__ Ah,
                                                     const bf16* __restrict__ Al,
                                                     const bf16* __restrict__ Bmh,
                                                     const bf16* __restrict__ Bml,
                                                     const bf16* __restrict__ Bfh,
                                                     const bf16* __restrict__ Bfl,
                                                     float* __restrict__ Cm,
                                                     float* __restrict__ Cf,
                                                     int M, int N, int K) {
    __shared__ bf16 sAh[4096], sAl[4096];
    __shared__ bf16 sMh[4096], sMl[4096];
    __shared__ bf16 sFh[4096], sFl[4096];

    const int tid  = threadIdx.x;
    const int wave = tid >> 6;
    const int lane = tid & 63;
    int n0, m0;
    xcd_tile(n0, m0);
    const int wm   = wave & 1;
    const int wn   = wave >> 1;

    floatx4 am[4][4], af[4][4];
#pragma unroll
    for (int i = 0; i < 4; ++i)
#pragma unroll
        for (int j = 0; j < 4; ++j) {
            am[i][j] = (floatx4){0.f, 0.f, 0.f, 0.f};
            af[i][j] = (floatx4){0.f, 0.f, 0.f, 0.f};
        }

    const int lr  = lane & 15;
    const int cc8 = (lane >> 4) << 3;
    const int cq  = cc8 >> 3;
    const int hsw = lr >> 1;

    for (int kt = 0; kt < K; kt += 32) {
#pragma unroll
        for (int i = 0; i < 2; ++i) {
            const int q = ((i * 4 + wave) << 6) + lane;
            const int p = q ^ ((q >> 3) & 7);
            const int r = p >> 2, c = p & 3;
            const int e = q << 3;
            const size_t ga = (size_t)(m0 + r) * K + kt + c * 8;
            const size_t gb = (size_t)(n0 + r) * K + kt + c * 8;
            load_lds16(&Ah[ga],  &sAh[e]);
            load_lds16(&Al[ga],  &sAl[e]);
            load_lds16(&Bmh[gb], &sMh[e]);
            load_lds16(&Bml[gb], &sMl[e]);
            load_lds16(&Bfh[gb], &sFh[e]);
            load_lds16(&Bfl[gb], &sFl[e]);
        }
        __syncthreads();

        bf16x8 ah[4], al[4];
#pragma unroll
        for (int mi = 0; mi < 4; ++mi) {
            const int ql  = ((wm * 64 + mi * 16 + lr) << 2) + cq;
            const int off = (ql ^ hsw) << 3;
            ah[mi] = *(const bf16x8*)&sAh[off];
            al[mi] = *(const bf16x8*)&sAl[off];
        }
#pragma unroll
        for (int ni = 0; ni < 4; ++ni) {
            const int ql  = ((wn * 64 + ni * 16 + lr) << 2) + cq;
            const int off = (ql ^ hsw) << 3;
            const bf16x8 mh = *(const bf16x8*)&sMh[off];
            const bf16x8 ml = *(const bf16x8*)&sMl[off];
            const bf16x8 fh = *(const bf16x8*)&sFh[off];
            const bf16x8 fl = *(const bf16x8*)&sFl[off];
#pragma unroll
            for (int mi = 0; mi < 4; ++mi) {
                am[mi][ni] = __builtin_amdgcn_mfma_f32_16x16x32_bf16(
                    ah[mi], mh, am[mi][ni], 0, 0, 0);
                am[mi][ni] = __builtin_amdgcn_mfma_f32_16x16x32_bf16(
                    al[mi], mh, am[mi][ni], 0, 0, 0);
                am[mi][ni] = __builtin_amdgcn_mfma_f32_16x16x32_bf16(
                    ah[mi], ml, am[mi][ni], 0, 0, 0);
                af[mi][ni] = __builtin_amdgcn_mfma_f32_16x16x32_bf16(
                    ah[mi], fh, af[mi][ni], 0, 0, 0);
                af[mi][ni] = __builtin_amdgcn_mfma_f32_16x16x32_bf16(
                    al[mi], fh, af[mi][ni], 0, 0, 0);
                af[mi][ni] = __builtin_amdgcn_mfma_f32_16x16x32_bf16(
                    ah[mi], fl, af[mi][ni], 0, 0, 0);
            }
        }
        __syncthreads();
    }

    const int rq = (lane >> 4) << 2;
    const int cl = lane & 15;
#pragma unroll
    for (int mi = 0; mi < 4; ++mi) {
#pragma unroll
        for (int ni = 0; ni < 4; ++ni) {
            const int col = n0 + wn * 64 + ni * 16 + cl;
#pragma unroll
            for (int r = 0; r < 4; ++r) {
                const int row = m0 + wm * 64 + mi * 16 + rq + r;
                const size_t idx = (size_t)row * N + col;
                Cm[idx] = am[mi][ni][r];
                Cf[idx] = af[mi][ni][r];
            }
        }
    }
}

// ---------------------------------------------------------------------------
// Combine: phase_lock = sigmoid(male . female); out = pl*male + (1-pl)*female
// ---------------------------------------------------------------------------
__global__ __launch_bounds__(256) void combine_kernel(const float* __restrict__ male,
                                                      const float* __restrict__ female,
                                                      float* __restrict__ out) {
    const int b = blockIdx.x;
    const int t = threadIdx.x;

    const floatx4* m4 = (const floatx4*)(male   + (size_t)b * D_OUT);
    const floatx4* f4 = (const floatx4*)(female + (size_t)b * D_OUT);
    const floatx4 mv0 = m4[t * 2], mv1 = m4[t * 2 + 1];
    const floatx4 fv0 = f4[t * 2], fv1 = f4[t * 2 + 1];

    float s = 0.f;
#pragma unroll
    for (int j = 0; j < 4; ++j) s += mv0[j] * fv0[j] + mv1[j] * fv1[j];
#pragma unroll
    for (int off = 32; off > 0; off >>= 1) s += __shfl_down(s, off, 64);

    __shared__ float red[4];
    const int wave = t >> 6, lane = t & 63;
    if (lane == 0) red[wave] = s;
    __syncthreads();
    const float dot = red[0] + red[1] + red[2] + red[3];
    const float pl  = 1.f / (1.f + expf(-dot));

    floatx4 o0, o1;
#pragma unroll
    for (int j = 0; j < 4; ++j) {
        o0[j] = pl * mv0[j] + (1.f - pl) * fv0[j];
        o1[j] = pl * mv1[j] + (1.f - pl) * fv1[j];
    }
    floatx4* o4 = (floatx4*)(out + (size_t)b * D_OUT);
    o4[t * 2]     = o0;
    o4[t * 2 + 1] = o1;
}

// ---------------------------------------------------------------------------
// Pipeline:  male = xo @ (Wm P Wfl)^T,  female = xo @ (Wfe_flip P Wfl)^T
// ---------------------------------------------------------------------------
extern "C" void kernel_launch(void* const* d_in, const int* in_sizes, int n_in,
                              void* d_out, int out_size, void* d_ws, size_t ws_size,
                              hipStream_t stream) {
    const float* x   = (const float*)d_in[0];
    const float* Wfl = (const float*)d_in[1]; // [7,512,2048] == [3584,2048]
    const float* Wm  = (const float*)d_in[2]; // [2048,3584]
    const float* Wfe = (const float*)d_in[3]; // [2048,3584]
    float* out = (float*)d_out;
    (void)in_sizes; (void)n_in; (void)out_size; (void)ws_size;

    char* ws = (char*)d_ws;
    bf16*  xo_hi   = (bf16*)(ws);                    // 4096x2048 = 16,777,216
    bf16*  xo_lo   = (bf16*)(ws + 16777216);         // 16,777,216
    bf16*  Wc_hi   = (bf16*)(ws + 33554432);         // 4096x2048 = 16,777,216
    bf16*  Wc_lo   = (bf16*)(ws + 50331648);         // 16,777,216 -> 67,108,864
    // overlay phase A (dead after gemm3_single8):
    bf16*  WflT_hi = (bf16*)(ws + 67108864);         // 2048x3584 = 14,680,064
    bf16*  WflT_lo = (bf16*)(ws + 81788928);         // -> 96,468,992
    bf16*  Wcat_hi = (bf16*)(ws + 96468992);         // 4096x3584 = 29,360,128
    bf16*  Wcat_lo = (bf16*)(ws + 125829120);        // -> 155,189,248
    // overlay phase B (after gemm3_single8):
    float* male    = (float*)(ws + 67108864);        // 4096x2048 f32 = 33,554,432
    float* female  = (float*)(ws + 100663296);       // -> 134,217,728

    // 1. fused prep: vesica(4096) + tsplit(1792) + wcat(7168) = 13056 blocks
    prep_kernel<<<13056, 256, 0, stream>>>(x, Wfl, Wm, Wfe,
                                           xo_hi, xo_lo,
                                           WflT_hi, WflT_lo,
                                           Wcat_hi, Wcat_lo);

    // 2. weight combine (8-phase): Wc[4096,2048] = Wcat @ WflT^T (K=3584)
    //    grid 16x16 = 256 blocks = 1/CU, 512 threads, 144KB LDS ring
    gemm3_single8<<<dim3(16, 16), 512, 0, stream>>>(
        Wcat_hi, Wcat_lo, WflT_hi, WflT_lo, Wc_hi, Wc_lo,
        2 * D_OUT, D_IN, D_HID);

    // 3. main dual GEMM: male/female = xo @ Wc^T  (K=2048, fp32 out)
    gemm3_dual<<<dim3(D_OUT / 128, B_DIM / 128), 256, 0, stream>>>(
        xo_hi, xo_lo,
        Wc_hi, Wc_lo,
        Wc_hi + (size_t)D_OUT * D_IN, Wc_lo + (size_t)D_OUT * D_IN,
        male, female, B_DIM, D_OUT, D_IN);

    // 4. sigmoid phase-lock blend (fp32 out)
    combine_kernel<<<B_DIM, 256, 0, stream>>>(male, female, out);
}